// Round 2
// baseline (1867.982 us; speedup 1.0000x reference)
//
#include <hip/hip_runtime.h>

#define NBATCH 256
#define SLEN   2048
#define NTAG   64
#define BOS_T  1
#define EOS_T  2

// bt rows: SLEN-1 = 2047 rows x 64 bytes = 131008, round to 131072
#define BT_BYTES 131072
#define LDS_BYTES (BT_BYTES + 2 * NTAG * 4)

__global__ __launch_bounds__(64, 1)
void crf_viterbi(const float* __restrict__ emissions,  // [B,S,C]
                 const float* __restrict__ mask,       // [B,S]
                 const float* __restrict__ trans,      // [C,C]
                 int* __restrict__ out)                // [B,S] int32 tags
{
    extern __shared__ unsigned char lds[];
    unsigned char* bt = lds;                       // [S-1][64] backpointers
    float* alpha = (float*)(lds + BT_BYTES);       // ping-pong [2][64]

    const int b = blockIdx.x;
    const int c = threadIdx.x;                     // current tag, 0..63

    // T column c in registers: tc[p] = T[p][c]  (static indexing only!)
    float tc[64];
    #pragma unroll
    for (int p = 0; p < 64; ++p) tc[p] = trans[p * NTAG + c];

    // length = sum(mask[b,:]) ; mask is left-contiguous 1s
    const float* mrow = mask + (size_t)b * SLEN;
    float msum = 0.f;
    #pragma unroll
    for (int k = 0; k < SLEN / 64; ++k) msum += mrow[c + k * 64];
    #pragma unroll
    for (int off = 32; off >= 1; off >>= 1) msum += __shfl_xor(msum, off, 64);
    const int len = (int)msum;                     // in [1024, 2048]

    const float* E = emissions + (size_t)b * SLEN * NTAG;

    // alpha0 = emissions[:,0] + T[BOS,:]
    alpha[c] = E[c] + tc[BOS_T];
    __syncthreads();

    // prefetch emissions for t=1
    float eNext = E[NTAG + c];

    int ping = 0;
    for (int t = 1; t < len; ++t) {
        float emit = eNext;
        int tn = (t + 1 < len) ? (t + 1) : t;      // clamp (valid addr re-read)
        eNext = E[tn * NTAG + c];                  // issued early, used next iter

        const float4* a4 = (const float4*)(alpha + ping * NTAG);

        // 4 independent chains over contiguous prev ranges [16j, 16j+16)
        float bestv[4];
        int   besti[4];
        #pragma unroll
        for (int j = 0; j < 4; ++j) {
            float bv = -3.402823466e38f;
            int   bi = 0;
            #pragma unroll
            for (int q = 0; q < 4; ++q) {
                float4 av = a4[j * 4 + q];
                const int p = j * 16 + q * 4;
                float cand;
                cand = av.x + tc[p + 0]; if (cand > bv) { bv = cand; bi = p + 0; }
                cand = av.y + tc[p + 1]; if (cand > bv) { bv = cand; bi = p + 1; }
                cand = av.z + tc[p + 2]; if (cand > bv) { bv = cand; bi = p + 2; }
                cand = av.w + tc[p + 3]; if (cand > bv) { bv = cand; bi = p + 3; }
            }
            bestv[j] = bv; besti[j] = bi;
        }
        // merge chains in ascending-prev order, strict > keeps first argmax
        float bv = bestv[0]; int bi = besti[0];
        if (bestv[1] > bv) { bv = bestv[1]; bi = besti[1]; }
        if (bestv[2] > bv) { bv = bestv[2]; bi = besti[2]; }
        if (bestv[3] > bv) { bv = bestv[3]; bi = besti[3]; }

        bt[(t - 1) * NTAG + c] = (unsigned char)bi;
        alpha[(ping ^ 1) * NTAG + c] = bv + emit;
        __syncthreads();
        ping ^= 1;
    }

    // final scores: alpha + T[:,EOS] ; T[c][EOS] = trans[c*64 + EOS]
    float fin = alpha[ping * NTAG + c] + trans[c * NTAG + EOS_T];

    // wave argmax: value desc, index asc (first occurrence)
    float v = fin; int idx = c;
    #pragma unroll
    for (int off = 1; off < 64; off <<= 1) {
        float ov = __shfl_xor(v, off, 64);
        int   oi = __shfl_xor(idx, off, 64);
        if (ov > v || (ov == v && oi < idx)) { v = ov; idx = oi; }
    }
    int cur = idx;                                  // best_last (wave-uniform)

    int* orow = out + (size_t)b * SLEN;
    // PAD tail: t in [len, S)
    for (int t = len + c; t < SLEN; t += 64) orow[t] = 0;
    if (c == 0) orow[len - 1] = cur;

    // backtrace through LDS backpointers (uniform addr -> broadcast read)
    for (int t = len - 2; t >= 0; --t) {
        cur = bt[t * NTAG + cur];
        if (c == 0) orow[t] = cur;
    }
}

extern "C" void kernel_launch(void* const* d_in, const int* in_sizes, int n_in,
                              void* d_out, int out_size, void* d_ws, size_t ws_size,
                              hipStream_t stream) {
    const float* emissions = (const float*)d_in[0];
    const float* mask      = (const float*)d_in[1];
    const float* trans     = (const float*)d_in[2];
    int* out = (int*)d_out;

    // allow >64KB dynamic LDS (idempotent; host-side, not a stream op)
    (void)hipFuncSetAttribute((const void*)crf_viterbi,
                              hipFuncAttributeMaxDynamicSharedMemorySize,
                              LDS_BYTES);

    crf_viterbi<<<NBATCH, 64, LDS_BYTES, stream>>>(emissions, mask, trans, out);
}